// Round 6
// baseline (520.726 us; speedup 1.0000x reference)
//
#include <hip/hip_runtime.h>
#include <math.h>

// ---------------- problem constants ----------------
#define N_TOK 16384        // B*T
#define HD    1024         // hidden
#define FD    1024         // expert ffn dim
#define NE    8            // experts
#define NA    (N_TOK * 2)  // assignments (top-2)
#define MBLK  256          // GEMM m-block rows
#define MAX_MB 136         // max m-block-table entries: 32768/256 + 8

typedef __attribute__((ext_vector_type(8))) short bf16x8;
typedef __attribute__((ext_vector_type(4))) short bf16x4;
typedef __attribute__((ext_vector_type(4))) float f32x4;

// ---------------- workspace layout (bytes) ----------------
#define WS_USAGE  0u
#define WS_COUNTS 64u                   // int[8]
#define WS_OFFS   128u                  // int[16]
#define WS_CURSOR 192u                  // int[8]
#define WS_TBLN   256u                  // int[1] (+pad)
#define WS_BLKE   320u                  // int[MAX_MB]
#define WS_BLKM   (WS_BLKE + 1088u)     // int[MAX_MB]
#define WS_TOKE   8192u                 // int[NA]
#define WS_TOKG   (WS_TOKE + NA * 4u)   // float[NA]
#define WS_TOKP   (WS_TOKG + NA * 4u)   // int[NA]
#define WS_ATOK   (WS_TOKP + NA * 4u)   // int[NA]
#define WS_AGATE  (WS_ATOK + NA * 4u)   // float[NA]
#define WS_XB     (1u << 20)                      // bf16[N_TOK*HD] 33.5 MB
#define WS_GWB    (WS_XB  + 33554432u)            // bf16[8M]
#define WS_UWB    (WS_GWB + 16777216u)            // bf16[8M]
#define WS_DWB    (WS_UWB + 16777216u)            // bf16[8M]
#define WS_HID    (WS_DWB + 16777216u)            // bf16[NA*FD] 67 MB
#define WS_Y      WS_XB   // alias: Y (bf16[NA*HD], 67 MB) overlays xb+gwb+uwb,
                          // which are dead once gemm1 completes (rebuilt every call)

__device__ __forceinline__ short f2b(float f) {  // fp32 -> bf16 RNE
    union { float f; unsigned u; } c;
    c.f = f;
    unsigned u = (c.u + 0x7fffu + ((c.u >> 16) & 1u)) >> 16;
    return (short)u;
}
__device__ __forceinline__ float b2f(short s) {
    union { unsigned u; float f; } c;
    c.u = ((unsigned)(unsigned short)s) << 16;
    return c.f;
}

// async 16B/lane global -> LDS (dest = wave-uniform base + lane*16)
__device__ __forceinline__ void gl_lds16(const short* g, short* l) {
    __builtin_amdgcn_global_load_lds(
        (const __attribute__((address_space(1))) unsigned int*)g,
        (__attribute__((address_space(3))) unsigned int*)l,
        16, 0, 0);
}

// ---------------- kernel 0: zero ws counters ----------------
__global__ void init_kernel(int* ws) {
    if (threadIdx.x < 64) ws[threadIdx.x] = 0;
}

// ---------------- kernel 1: fp32 -> bf16, all 3 weight tensors ----------------
__global__ __launch_bounds__(256) void cvt3_kernel(
    const float* __restrict__ gw, const float* __restrict__ uw, const float* __restrict__ dw,
    short* __restrict__ gwb, short* __restrict__ uwb, short* __restrict__ dwb) {
    const float* in  = (blockIdx.y == 0) ? gw  : (blockIdx.y == 1) ? uw  : dw;
    short*       out = (blockIdx.y == 0) ? gwb : (blockIdx.y == 1) ? uwb : dwb;
    const int i = blockIdx.x * 256 + threadIdx.x;   // 8 elems/thread, 8M elems
    const float4 a = ((const float4*)in)[2 * i];
    const float4 b = ((const float4*)in)[2 * i + 1];
    bf16x8 o;
    o[0] = f2b(a.x); o[1] = f2b(a.y); o[2] = f2b(a.z); o[3] = f2b(a.w);
    o[4] = f2b(b.x); o[5] = f2b(b.y); o[6] = f2b(b.z); o[7] = f2b(b.w);
    ((bf16x8*)out)[i] = o;
}

// ---------------- kernel 2: router (wave/token, fp32) + fused x->bf16 ----------------
__global__ __launch_bounds__(256) void router_kernel(
    const float* __restrict__ x, const float* __restrict__ rw,
    float* __restrict__ usage, int* __restrict__ counts,
    int* __restrict__ tok_e, float* __restrict__ tok_g, short* __restrict__ xb)
{
    __shared__ float rws[NE * HD];
    __shared__ float usage_s[NE];
    __shared__ int counts_s[NE];
    const int tid = threadIdx.x;
    if (tid < NE) { usage_s[tid] = 0.f; counts_s[tid] = 0; }
    for (int c = tid; c < NE * HD / 4; c += 256)
        ((float4*)rws)[c] = ((const float4*)rw)[c];
    __syncthreads();

    const int wave = tid >> 6, lane = tid & 63;
    const int t = blockIdx.x * 4 + wave;
    float acc[NE];
#pragma unroll
    for (int e = 0; e < NE; ++e) acc[e] = 0.f;
    const float* xrow = x + (size_t)t * HD;
    short* xbrow = xb + (size_t)t * HD;
#pragma unroll
    for (int j = 0; j < 4; ++j) {
        const int h0 = (j * 64 + lane) * 4;
        const float4 xv = *(const float4*)(xrow + h0);
        bf16x4 xc;
        xc[0] = f2b(xv.x); xc[1] = f2b(xv.y); xc[2] = f2b(xv.z); xc[3] = f2b(xv.w);
        *(bf16x4*)(xbrow + h0) = xc;
#pragma unroll
        for (int e = 0; e < NE; ++e) {
            const float4 wv = *(const float4*)&rws[e * HD + h0];
            acc[e] += xv.x * wv.x + xv.y * wv.y + xv.z * wv.z + xv.w * wv.w;
        }
    }
#pragma unroll
    for (int e = 0; e < NE; ++e)
#pragma unroll
        for (int off = 32; off > 0; off >>= 1)
            acc[e] += __shfl_xor(acc[e], off, 64);

    if (lane == 0) {
        float mx = acc[0];
        for (int e = 1; e < NE; ++e) mx = fmaxf(mx, acc[e]);
        float p[NE], Z = 0.f;
        for (int e = 0; e < NE; ++e) { p[e] = expf(acc[e] - mx); Z += p[e]; }
        const float invZ = 1.f / Z;
        for (int e = 0; e < NE; ++e) { p[e] *= invZ; atomicAdd(&usage_s[e], p[e]); }
        int i0 = 0;
        for (int e = 1; e < NE; ++e) if (acc[e] > acc[i0]) i0 = e;
        int i1 = (i0 == 0) ? 1 : 0;
        for (int e = 0; e < NE; ++e) if (e != i0 && acc[e] > acc[i1]) i1 = e;
        const float gs = 1.f / (p[i0] + p[i1]);
        tok_e[2 * t] = i0;  tok_e[2 * t + 1] = i1;
        tok_g[2 * t] = p[i0] * gs;  tok_g[2 * t + 1] = p[i1] * gs;
        atomicAdd(&counts_s[i0], 1); atomicAdd(&counts_s[i1], 1);
    }
    __syncthreads();
    if (tid < NE) {
        atomicAdd(&usage[tid], usage_s[tid]);
        atomicAdd(&counts[tid], counts_s[tid]);
    }
}

// ---------------- kernel 3: offsets + lb_loss + m-block table (256-row) ----------------
__global__ void offsets_lb_kernel(const float* __restrict__ usage,
                                  const int* __restrict__ counts,
                                  int* __restrict__ offs, float* __restrict__ lb_out,
                                  int* __restrict__ tbl_n, int* __restrict__ blk_e,
                                  int* __restrict__ blk_m)
{
    if (threadIdx.x == 0) {
        int acc = 0, nb = 0;
        for (int e = 0; e < NE; ++e) {
            offs[e] = acc;
            const int c = counts[e];
            acc += c;
            for (int mb = 0; mb < c; mb += MBLK) { blk_e[nb] = e; blk_m[nb] = mb; ++nb; }
        }
        offs[NE] = acc;
        tbl_n[0] = nb;
        float s = 0.f;
        for (int e = 0; e < NE; ++e) {
            const float u = usage[e] * (1.f / (float)N_TOK);
            s += u * u;
        }
        lb_out[0] = 0.01f * 8.f * s;
    }
}

// ---------------- kernel 4: scatter — block-aggregated atomics (G12) ----------------
__global__ __launch_bounds__(256) void scatter_kernel(
    const int* __restrict__ tok_e, const float* __restrict__ tok_g,
    const int* __restrict__ offs, int* __restrict__ cursor,
    int* __restrict__ asg_tok, float* __restrict__ asg_g,
    int* __restrict__ tok_pos)
{
    __shared__ int cnt_s[NE];
    __shared__ int base_s[NE];
    const int tid = threadIdx.x;
    if (tid < NE) cnt_s[tid] = 0;
    __syncthreads();

    const int idx = blockIdx.x * 256 + tid;
    const int e = tok_e[idx];
    const int local = atomicAdd(&cnt_s[e], 1);   // LDS atomic: cheap
    __syncthreads();

    if (tid < NE) base_s[tid] = atomicAdd(&cursor[tid], cnt_s[tid]);  // 8 global atomics/block
    __syncthreads();

    const int pos = offs[e] + base_s[e] + local;
    asg_tok[pos] = idx >> 1;
    asg_g[pos] = tok_g[idx];
    tok_pos[idx] = pos;
}

// ============================================================================
// Grouped GEMMs — m97-style single-buffer loop, ENLARGED wave tile.
// LDS-BW model: MfmaUtil_ceiling = 1.21 cyc/MFMA / (reads_per_MFMA / 256 B/cyc).
// Old wave 64x64 -> 500 B/MFMA -> 62% ceiling (measured 47%). New wave 128x64
// -> 375 B/MFMA -> ~82% ceiling. Cost: acc 128 VGPR/wave, 48 KiB LDS ->
// 2 blocks/CU (8 waves) instead of 4. b-frags loaded per slice; a-frag loaded
// one-at-a-time inside mi loop to cap live registers (~200 VGPR, no spill).
// XCD swizzle unchanged (bijective: grids divisible by 8).
// ============================================================================

// ---------------- kernel 5: grouped GEMM1 — hid = silu(x@gateT)*(x@upT) ----------------
// BM=256, BN=64 dual-B. 4 waves 2Mx2N; wave tile 128M x (32N gate + 32N up).
// Grid: 1D, 16 n-panels x MAX_MB m-blocks = 2176 (divisible by 8).
__global__ __launch_bounds__(256, 2) void gemm1_kernel(
    const short* __restrict__ xb, const short* __restrict__ gate_b,
    const short* __restrict__ up_b, const int* __restrict__ counts,
    const int* __restrict__ offs, const int* __restrict__ asg_tok,
    const int* __restrict__ tbl_n, const int* __restrict__ blk_e,
    const int* __restrict__ blk_m, short* __restrict__ hid)
{
    __shared__ short As[256 * 64];   // 32 KB
    __shared__ short Bg[64 * 64];    //  8 KB
    __shared__ short Bu[64 * 64];    //  8 KB

    const int wg  = blockIdx.x;
    const int swz = (wg & 7) * (16 * MAX_MB / 8) + (wg >> 3);
    const int m_id = swz >> 4;          // 16 n-panels per m-block
    const int n_base = (swz & 15) * 64;
    if (m_id >= tbl_n[0]) return;
    const int e = blk_e[m_id];
    const int m_base = blk_m[m_id];
    const int n_e = counts[e];
    const int off_e = offs[e];

    const int tid = threadIdx.x;
    const int wave = tid >> 6, lane = tid & 63;
    const int lr = lane >> 3, lg = lane & 7;
    const int sg = lg ^ lr;

    const short* a_src[8];
#pragma unroll
    for (int j = 0; j < 8; ++j) {
        const int r = j * 32 + wave * 8 + lr;          // 0..255
        const int gm = m_base + r;
        const int tok = asg_tok[off_e + (gm < n_e ? gm : 0)];
        a_src[j] = xb + (size_t)tok * HD + sg * 8;
    }
    const short* gwp = gate_b + (size_t)e * FD * HD;
    const short* uwp = up_b + (size_t)e * FD * HD;
    const short* bg_src[2]; const short* bu_src[2];
#pragma unroll
    for (int j = 0; j < 2; ++j) {
        const int r = j * 32 + wave * 8 + lr;          // 0..63
        bg_src[j] = gwp + (size_t)(n_base + r) * HD + sg * 8;
        bu_src[j] = uwp + (size_t)(n_base + r) * HD + sg * 8;
    }

    const int wm = (wave >> 1) * 128;   // 2 M-waves (128 rows each)
    const int wn = (wave & 1) * 32;     // 2 N-waves (32 cols each, gate AND up)
    const int quad = lane >> 4, l16 = lane & 15;

    f32x4 accG[8][2], accU[8][2];
#pragma unroll
    for (int mi = 0; mi < 8; ++mi)
#pragma unroll
        for (int ni = 0; ni < 2; ++ni) { accG[mi][ni] = (f32x4){0,0,0,0}; accU[mi][ni] = (f32x4){0,0,0,0}; }

    for (int t = 0; t < 16; ++t) {
        const int k0 = t * 64;
#pragma unroll
        for (int j = 0; j < 8; ++j)
            gl_lds16(a_src[j] + k0, &As[(j * 32 + wave * 8) * 64]);
#pragma unroll
        for (int j = 0; j < 2; ++j) {
            gl_lds16(bg_src[j] + k0, &Bg[(j * 32 + wave * 8) * 64]);
            gl_lds16(bu_src[j] + k0, &Bu[(j * 32 + wave * 8) * 64]);
        }
        __syncthreads();
#pragma unroll
        for (int kk8 = 0; kk8 < 8; kk8 += 4) {
            bf16x8 bg[2], bu[2];
#pragma unroll
            for (int ni = 0; ni < 2; ++ni) {
                const int row = wn + ni * 16 + l16;
                const int pg = (kk8 + quad) ^ (row & 7);
                bg[ni] = *(const bf16x8*)&Bg[row * 64 + pg * 8];
                bu[ni] = *(const bf16x8*)&Bu[row * 64 + pg * 8];
            }
#pragma unroll
            for (int mi = 0; mi < 8; ++mi) {
                const int row = wm + mi * 16 + l16;
                const int pg = (kk8 + quad) ^ (row & 7);
                const bf16x8 a = *(const bf16x8*)&As[row * 64 + pg * 8];
#pragma unroll
                for (int ni = 0; ni < 2; ++ni) {
                    accG[mi][ni] = __builtin_amdgcn_mfma_f32_16x16x32_bf16(a, bg[ni], accG[mi][ni], 0, 0, 0);
                    accU[mi][ni] = __builtin_amdgcn_mfma_f32_16x16x32_bf16(a, bu[ni], accU[mi][ni], 0, 0, 0);
                }
            }
        }
        __syncthreads();
    }

#pragma unroll
    for (int mi = 0; mi < 8; ++mi) {
#pragma unroll
        for (int r = 0; r < 4; ++r) {
            const int gm = m_base + wm + mi * 16 + quad * 4 + r;
            if (gm < n_e) {
#pragma unroll
                for (int ni = 0; ni < 2; ++ni) {
                    const int f = n_base + wn + ni * 16 + l16;
                    const float gv = accG[mi][ni][r];
                    const float uv = accU[mi][ni][r];
                    hid[(size_t)(off_e + gm) * FD + f] = f2b((gv / (1.f + expf(-gv))) * uv);
                }
            }
        }
    }
}

// ---------------- kernel 6: grouped GEMM2 — Y[pos] = gate*(hid@downT), bf16 ----------------
// BM=256, BN=128. 4 waves 2Mx2N; wave tile 128M x 64N.
// Grid: 1D, 8 n-panels x MAX_MB = 1088 (divisible by 8).
__global__ __launch_bounds__(256, 2) void gemm2_kernel(
    const short* __restrict__ hid, const short* __restrict__ down_b,
    const int* __restrict__ counts, const int* __restrict__ offs,
    const float* __restrict__ asg_g, const int* __restrict__ tbl_n,
    const int* __restrict__ blk_e, const int* __restrict__ blk_m,
    short* __restrict__ Y)
{
    __shared__ short As[256 * 64];   // 32 KB
    __shared__ short Bs[128 * 64];   // 16 KB

    const int wg  = blockIdx.x;
    const int swz = (wg & 7) * (8 * MAX_MB / 8) + (wg >> 3);
    const int m_id = swz >> 3;          // 8 n-panels per m-block
    const int n_base = (swz & 7) * 128;
    if (m_id >= tbl_n[0]) return;
    const int e = blk_e[m_id];
    const int m_base = blk_m[m_id];
    const int n_e = counts[e];
    const int off_e = offs[e];

    const int tid = threadIdx.x;
    const int wave = tid >> 6, lane = tid & 63;
    const int lr = lane >> 3, lg = lane & 7;
    const int sg = lg ^ lr;

    const short* a_src[8]; const short* b_src[4];
    const short* bwp = down_b + (size_t)e * HD * FD;
#pragma unroll
    for (int j = 0; j < 8; ++j) {
        const int r = j * 32 + wave * 8 + lr;          // 0..255
        const int gm = m_base + r;
        const size_t srow = (size_t)(off_e + (gm < n_e ? gm : 0));
        a_src[j] = hid + srow * FD + sg * 8;
    }
#pragma unroll
    for (int j = 0; j < 4; ++j) {
        const int r = j * 32 + wave * 8 + lr;          // 0..127
        b_src[j] = bwp + (size_t)(n_base + r) * FD + sg * 8;
    }

    const int wm = (wave >> 1) * 128;
    const int wn = (wave & 1) * 64;
    const int quad = lane >> 4, l16 = lane & 15;

    f32x4 acc[8][4];
#pragma unroll
    for (int mi = 0; mi < 8; ++mi)
#pragma unroll
        for (int ni = 0; ni < 4; ++ni) acc[mi][ni] = (f32x4){0,0,0,0};

    for (int t = 0; t < 16; ++t) {
        const int k0 = t * 64;
#pragma unroll
        for (int j = 0; j < 8; ++j)
            gl_lds16(a_src[j] + k0, &As[(j * 32 + wave * 8) * 64]);
#pragma unroll
        for (int j = 0; j < 4; ++j)
            gl_lds16(b_src[j] + k0, &Bs[(j * 32 + wave * 8) * 64]);
        __syncthreads();
#pragma unroll
        for (int kk8 = 0; kk8 < 8; kk8 += 4) {
            bf16x8 b[4];
#pragma unroll
            for (int ni = 0; ni < 4; ++ni) {
                const int row = wn + ni * 16 + l16;
                const int pg = (kk8 + quad) ^ (row & 7);
                b[ni] = *(const bf16x8*)&Bs[row * 64 + pg * 8];
            }
#pragma unroll
            for (int mi = 0; mi < 8; ++mi) {
                const int row = wm + mi * 16 + l16;
                const int pg = (kk8 + quad) ^ (row & 7);
                const bf16x8 a = *(const bf16x8*)&As[row * 64 + pg * 8];
#pragma unroll
                for (int ni = 0; ni < 4; ++ni)
                    acc[mi][ni] = __builtin_amdgcn_mfma_f32_16x16x32_bf16(a, b[ni], acc[mi][ni], 0, 0, 0);
            }
        }
        __syncthreads();
    }

#pragma unroll
    for (int mi = 0; mi < 8; ++mi) {
#pragma unroll
        for (int r = 0; r < 4; ++r) {
            const int gm = m_base + wm + mi * 16 + quad * 4 + r;
            if (gm < n_e) {
                const int pos = off_e + gm;
                const float gate = asg_g[pos];
                short* yrow = Y + (size_t)pos * HD;
#pragma unroll
                for (int ni = 0; ni < 4; ++ni) {
                    const int n = n_base + wn + ni * 16 + l16;
                    yrow[n] = f2b(acc[mi][ni][r] * gate);
                }
            }
        }
    }
}

// ---------------- kernel 7: combine — out[t] = Y[p0] + Y[p1] (fp32) ----------------
__global__ __launch_bounds__(256) void combine_kernel(
    const short* __restrict__ Y, const int* __restrict__ tok_pos, float* __restrict__ out)
{
    const int g = blockIdx.x * 256 + threadIdx.x;   // 8 elems/thread
    const int t  = g >> 7;
    const int w8 = (g & 127) * 8;
    const int p0 = tok_pos[2 * t], p1 = tok_pos[2 * t + 1];
    const bf16x8 y0 = *(const bf16x8*)(Y + (size_t)p0 * HD + w8);
    const bf16x8 y1 = *(const bf16x8*)(Y + (size_t)p1 * HD + w8);
    float4 o0, o1;
    o0.x = b2f(y0[0]) + b2f(y1[0]); o0.y = b2f(y0[1]) + b2f(y1[1]);
    o0.z = b2f(y0[2]) + b2f(y1[2]); o0.w = b2f(y0[3]) + b2f(y1[3]);
    o1.x = b2f(y0[4]) + b2f(y1[4]); o1.y = b2f(y0[5]) + b2f(y1[5]);
    o1.z = b2f(y0[6]) + b2f(y1[6]); o1.w = b2f(y0[7]) + b2f(y1[7]);
    float* orow = out + (size_t)t * HD + w8;
    *(float4*)orow = o0;
    *(float4*)(orow + 4) = o1;
}

// ---------------- launch ----------------
extern "C" void kernel_launch(void* const* d_in, const int* in_sizes, int n_in,
                              void* d_out, int out_size, void* d_ws, size_t ws_size,
                              hipStream_t stream)
{
    const float* x  = (const float*)d_in[0];
    const float* rw = (const float*)d_in[1];
    const float* gw = (const float*)d_in[2];
    const float* uw = (const float*)d_in[3];
    const float* dw = (const float*)d_in[4];
    float* out = (float*)d_out;

    char* ws = (char*)d_ws;
    float* usage = (float*)(ws + WS_USAGE);
    int* counts  = (int*)(ws + WS_COUNTS);
    int* offs    = (int*)(ws + WS_OFFS);
    int* cursor  = (int*)(ws + WS_CURSOR);
    int* tbl_n   = (int*)(ws + WS_TBLN);
    int* blk_e   = (int*)(ws + WS_BLKE);
    int* blk_m   = (int*)(ws + WS_BLKM);
    int* tok_e   = (int*)(ws + WS_TOKE);
    float* tok_g = (float*)(ws + WS_TOKG);
    int* tok_pos = (int*)(ws + WS_TOKP);
    int* asg_tok = (int*)(ws + WS_ATOK);
    float* asg_g = (float*)(ws + WS_AGATE);
    short* xb    = (short*)(ws + WS_XB);
    short* gwb   = (short*)(ws + WS_GWB);
    short* uwb   = (short*)(ws + WS_UWB);
    short* dwb   = (short*)(ws + WS_DWB);
    short* hid   = (short*)(ws + WS_HID);
    short* Y     = (short*)(ws + WS_Y);   // aliases xb/gwb/uwb (dead after gemm1)

    init_kernel<<<1, 64, 0, stream>>>((int*)ws);
    cvt3_kernel<<<dim3((NE * FD * HD / 8) / 256, 3), 256, 0, stream>>>(gw, uw, dw, gwb, uwb, dwb);
    router_kernel<<<N_TOK / 4, 256, 0, stream>>>(x, rw, usage, counts, tok_e, tok_g, xb);
    offsets_lb_kernel<<<1, 64, 0, stream>>>(usage, counts, offs, out + 16777216,
                                            tbl_n, blk_e, blk_m);
    scatter_kernel<<<NA / 256, 256, 0, stream>>>(tok_e, tok_g, offs, cursor,
                                                 asg_tok, asg_g, tok_pos);
    gemm1_kernel<<<16 * MAX_MB, 256, 0, stream>>>(
        xb, gwb, uwb, counts, offs, asg_tok, tbl_n, blk_e, blk_m, hid);
    gemm2_kernel<<<8 * MAX_MB, 256, 0, stream>>>(
        hid, dwb, counts, offs, asg_g, tbl_n, blk_e, blk_m, Y);
    combine_kernel<<<(N_TOK * HD / 8) / 256, 256, 0, stream>>>(Y, tok_pos, out);
}

// Round 9
// 464.180 us; speedup vs baseline: 1.1218x; 1.1218x over previous
//
#include <hip/hip_runtime.h>
#include <math.h>

// ---------------- problem constants ----------------
#define N_TOK 16384        // B*T
#define HD    1024         // hidden
#define FD    1024         // expert ffn dim
#define NE    8            // experts
#define NA    (N_TOK * 2)  // assignments (top-2)
#define MBLK  128          // GEMM m-block rows
#define MAX_MB 264         // max m-block-table entries: 32768/128 + 8

typedef __attribute__((ext_vector_type(8))) short bf16x8;
typedef __attribute__((ext_vector_type(4))) short bf16x4;
typedef __attribute__((ext_vector_type(4))) float f32x4;

// ---------------- workspace layout (bytes) ----------------
#define WS_USAGE  0u
#define WS_COUNTS 64u                   // int[8]
#define WS_OFFS   128u                  // int[16]
#define WS_CURSOR 192u                  // int[8]
#define WS_TBLN   256u                  // int[1] (+pad)
#define WS_BLKE   320u                  // int[MAX_MB]
#define WS_BLKM   (WS_BLKE + 1088u)     // int[MAX_MB]
#define WS_TOKE   8192u                 // int[NA]
#define WS_TOKG   (WS_TOKE + NA * 4u)   // float[NA]
#define WS_TOKP   (WS_TOKG + NA * 4u)   // int[NA]
#define WS_ATOK   (WS_TOKP + NA * 4u)   // int[NA]
#define WS_AGATE  (WS_ATOK + NA * 4u)   // float[NA]
#define WS_XB     (1u << 20)                      // bf16[N_TOK*HD] 33.5 MB
#define WS_GWB    (WS_XB  + 33554432u)            // bf16[8M]
#define WS_UWB    (WS_GWB + 16777216u)            // bf16[8M]
#define WS_DWB    (WS_UWB + 16777216u)            // bf16[8M]
#define WS_HID    (WS_DWB + 16777216u)            // bf16[NA*FD] 67 MB
#define WS_Y      WS_XB   // alias: Y (bf16[NA*HD], 67 MB) overlays xb+gwb+uwb,
                          // which are dead once gemm1 completes (rebuilt every call)

__device__ __forceinline__ short f2b(float f) {  // fp32 -> bf16 RNE
    union { float f; unsigned u; } c;
    c.f = f;
    unsigned u = (c.u + 0x7fffu + ((c.u >> 16) & 1u)) >> 16;
    return (short)u;
}
__device__ __forceinline__ float b2f(short s) {
    union { unsigned u; float f; } c;
    c.u = ((unsigned)(unsigned short)s) << 16;
    return c.f;
}

// async 16B/lane global -> LDS (dest = wave-uniform base + lane*16)
__device__ __forceinline__ void gl_lds16(const short* g, short* l) {
    __builtin_amdgcn_global_load_lds(
        (const __attribute__((address_space(1))) unsigned int*)g,
        (__attribute__((address_space(3))) unsigned int*)l,
        16, 0, 0);
}

// ---------------- kernel 1: fp32 -> bf16 (3 weight tensors) + init fold ----------------
// Block (0,0) also zeroes the 64 ws counter ints (init_kernel folded in; stream
// order guarantees completion before router_kernel reads/writes them).
__global__ __launch_bounds__(256) void cvt3_kernel(
    const float* __restrict__ gw, const float* __restrict__ uw, const float* __restrict__ dw,
    short* __restrict__ gwb, short* __restrict__ uwb, short* __restrict__ dwb,
    int* __restrict__ ws_counters) {
    if (blockIdx.x == 0 && blockIdx.y == 0 && threadIdx.x < 64)
        ws_counters[threadIdx.x] = 0;
    const float* in  = (blockIdx.y == 0) ? gw  : (blockIdx.y == 1) ? uw  : dw;
    short*       out = (blockIdx.y == 0) ? gwb : (blockIdx.y == 1) ? uwb : dwb;
    const int i = blockIdx.x * 256 + threadIdx.x;   // 8 elems/thread, 8M elems
    const float4 a = ((const float4*)in)[2 * i];
    const float4 b = ((const float4*)in)[2 * i + 1];
    bf16x8 o;
    o[0] = f2b(a.x); o[1] = f2b(a.y); o[2] = f2b(a.z); o[3] = f2b(a.w);
    o[4] = f2b(b.x); o[5] = f2b(b.y); o[6] = f2b(b.z); o[7] = f2b(b.w);
    ((bf16x8*)out)[i] = o;
}

// ---------------- kernel 2: router (wave/token, fp32) + fused x->bf16 ----------------
// 512 thr / 8 waves / 8 tokens per block: halves rws staging per token and
// halves block count vs the 256-thr version. Per-wave logic unchanged.
__global__ __launch_bounds__(512) void router_kernel(
    const float* __restrict__ x, const float* __restrict__ rw,
    float* __restrict__ usage, int* __restrict__ counts,
    int* __restrict__ tok_e, float* __restrict__ tok_g, short* __restrict__ xb)
{
    __shared__ float rws[NE * HD];
    __shared__ float usage_s[NE];
    __shared__ int counts_s[NE];
    const int tid = threadIdx.x;
    if (tid < NE) { usage_s[tid] = 0.f; counts_s[tid] = 0; }
    for (int c = tid; c < NE * HD / 4; c += 512)
        ((float4*)rws)[c] = ((const float4*)rw)[c];
    __syncthreads();

    const int wave = tid >> 6, lane = tid & 63;
    const int t = blockIdx.x * 8 + wave;
    float acc[NE];
#pragma unroll
    for (int e = 0; e < NE; ++e) acc[e] = 0.f;
    const float* xrow = x + (size_t)t * HD;
    short* xbrow = xb + (size_t)t * HD;
#pragma unroll
    for (int j = 0; j < 4; ++j) {
        const int h0 = (j * 64 + lane) * 4;
        const float4 xv = *(const float4*)(xrow + h0);
        bf16x4 xc;
        xc[0] = f2b(xv.x); xc[1] = f2b(xv.y); xc[2] = f2b(xv.z); xc[3] = f2b(xv.w);
        *(bf16x4*)(xbrow + h0) = xc;
#pragma unroll
        for (int e = 0; e < NE; ++e) {
            const float4 wv = *(const float4*)&rws[e * HD + h0];
            acc[e] += xv.x * wv.x + xv.y * wv.y + xv.z * wv.z + xv.w * wv.w;
        }
    }
#pragma unroll
    for (int e = 0; e < NE; ++e)
#pragma unroll
        for (int off = 32; off > 0; off >>= 1)
            acc[e] += __shfl_xor(acc[e], off, 64);

    if (lane == 0) {
        float mx = acc[0];
        for (int e = 1; e < NE; ++e) mx = fmaxf(mx, acc[e]);
        float p[NE], Z = 0.f;
        for (int e = 0; e < NE; ++e) { p[e] = expf(acc[e] - mx); Z += p[e]; }
        const float invZ = 1.f / Z;
        for (int e = 0; e < NE; ++e) { p[e] *= invZ; atomicAdd(&usage_s[e], p[e]); }
        int i0 = 0;
        for (int e = 1; e < NE; ++e) if (acc[e] > acc[i0]) i0 = e;
        int i1 = (i0 == 0) ? 1 : 0;
        for (int e = 0; e < NE; ++e) if (e != i0 && acc[e] > acc[i1]) i1 = e;
        const float gs = 1.f / (p[i0] + p[i1]);
        tok_e[2 * t] = i0;  tok_e[2 * t + 1] = i1;
        tok_g[2 * t] = p[i0] * gs;  tok_g[2 * t + 1] = p[i1] * gs;
        atomicAdd(&counts_s[i0], 1); atomicAdd(&counts_s[i1], 1);
    }
    __syncthreads();
    if (tid < NE) {
        atomicAdd(&usage[tid], usage_s[tid]);
        atomicAdd(&counts[tid], counts_s[tid]);
    }
}

// ---------------- kernel 3: offsets + lb_loss + m-block table ----------------
__global__ void offsets_lb_kernel(const float* __restrict__ usage,
                                  const int* __restrict__ counts,
                                  int* __restrict__ offs, float* __restrict__ lb_out,
                                  int* __restrict__ tbl_n, int* __restrict__ blk_e,
                                  int* __restrict__ blk_m)
{
    if (threadIdx.x == 0) {
        int acc = 0, nb = 0;
        for (int e = 0; e < NE; ++e) {
            offs[e] = acc;
            const int c = counts[e];
            acc += c;
            for (int mb = 0; mb < c; mb += MBLK) { blk_e[nb] = e; blk_m[nb] = mb; ++nb; }
        }
        offs[NE] = acc;
        tbl_n[0] = nb;
        float s = 0.f;
        for (int e = 0; e < NE; ++e) {
            const float u = usage[e] * (1.f / (float)N_TOK);
            s += u * u;
        }
        lb_out[0] = 0.01f * 8.f * s;
    }
}

// ---------------- kernel 4: scatter — block-aggregated atomics (G12) ----------------
__global__ __launch_bounds__(256) void scatter_kernel(
    const int* __restrict__ tok_e, const float* __restrict__ tok_g,
    const int* __restrict__ offs, int* __restrict__ cursor,
    int* __restrict__ asg_tok, float* __restrict__ asg_g,
    int* __restrict__ tok_pos)
{
    __shared__ int cnt_s[NE];
    __shared__ int base_s[NE];
    const int tid = threadIdx.x;
    if (tid < NE) cnt_s[tid] = 0;
    __syncthreads();

    const int idx = blockIdx.x * 256 + tid;
    const int e = tok_e[idx];
    const int local = atomicAdd(&cnt_s[e], 1);   // LDS atomic: cheap
    __syncthreads();

    if (tid < NE) base_s[tid] = atomicAdd(&cursor[tid], cnt_s[tid]);  // 8 global atomics/block
    __syncthreads();

    const int pos = offs[e] + base_s[e] + local;
    asg_tok[pos] = idx >> 1;
    asg_g[pos] = tok_g[idx];
    tok_pos[idx] = pos;
}

// ============================================================================
// Grouped GEMMs — ROUND-5 PROVEN GEOMETRY (measured 962 TF effective, above
// every grouped-GEMM reference in the evidence base; m248 grouped 8-phase =
// 848 TF, so deeper pipelining does NOT transfer here). m97 structure: single
// 32 KiB LDS buffer, STAGE -> sync -> compute -> sync, 256 thr / 4 waves,
// wave tile 64x64, batched frag loads (8 independent ds_reads then 16
// independent MFMAs — do NOT interleave a-loads into the MFMA loop, round-6
// lesson), 4 blocks/CU TLP covers the barrier drain. XCD-swizzled 1D grid.
// ============================================================================

// ---------------- kernel 5: grouped GEMM1 — hid = silu(x@gateT)*(x@upT) ----------------
// BM=128, BN=64 dual-B. Wave tile 64M x 32N for BOTH gate and up.
// Grid: 1D, 16 n-panels x MAX_MB m-blocks = 4224 (divisible by 8).
__global__ __launch_bounds__(256, 4) void gemm1_kernel(
    const short* __restrict__ xb, const short* __restrict__ gate_b,
    const short* __restrict__ up_b, const int* __restrict__ counts,
    const int* __restrict__ offs, const int* __restrict__ asg_tok,
    const int* __restrict__ tbl_n, const int* __restrict__ blk_e,
    const int* __restrict__ blk_m, short* __restrict__ hid)
{
    __shared__ short As[128 * 64];
    __shared__ short Bg[64 * 64];
    __shared__ short Bu[64 * 64];

    // XCD swizzle: wg -> (xcd, idx) -> swz; same XCD gets consecutive swz.
    const int wg  = blockIdx.x;
    const int swz = (wg & 7) * (16 * MAX_MB / 8) + (wg >> 3);
    const int m_id = swz >> 4;          // 16 n-panels per m-block
    const int n_base = (swz & 15) * 64;
    if (m_id >= tbl_n[0]) return;
    const int e = blk_e[m_id];
    const int m_base = blk_m[m_id];
    const int n_e = counts[e];
    const int off_e = offs[e];

    const int tid = threadIdx.x;
    const int wave = tid >> 6, lane = tid & 63;
    const int lr = lane >> 3, lg = lane & 7;
    const int sg = lg ^ lr;

    const short* a_src[4];
#pragma unroll
    for (int j = 0; j < 4; ++j) {
        const int r = wave * 32 + j * 8 + lr;
        const int gm = m_base + r;
        const int tok = asg_tok[off_e + (gm < n_e ? gm : 0)];
        a_src[j] = xb + (size_t)tok * HD + sg * 8;
    }
    const short* gwp = gate_b + (size_t)e * FD * HD;
    const short* uwp = up_b + (size_t)e * FD * HD;
    const short* bg_src[2]; const short* bu_src[2];
#pragma unroll
    for (int j = 0; j < 2; ++j) {
        const int r = wave * 16 + j * 8 + lr;
        bg_src[j] = gwp + (size_t)(n_base + r) * HD + sg * 8;
        bu_src[j] = uwp + (size_t)(n_base + r) * HD + sg * 8;
    }

    const int wm = (wave >> 1) * 64;
    const int wn = (wave & 1) * 32;
    const int quad = lane >> 4, l16 = lane & 15;

    f32x4 accG[4][2], accU[4][2];
#pragma unroll
    for (int mi = 0; mi < 4; ++mi)
#pragma unroll
        for (int ni = 0; ni < 2; ++ni) { accG[mi][ni] = (f32x4){0,0,0,0}; accU[mi][ni] = (f32x4){0,0,0,0}; }

    for (int t = 0; t < 16; ++t) {
        const int k0 = t * 64;
#pragma unroll
        for (int j = 0; j < 4; ++j)
            gl_lds16(a_src[j] + k0, &As[(wave * 32 + j * 8) * 64]);
#pragma unroll
        for (int j = 0; j < 2; ++j) {
            gl_lds16(bg_src[j] + k0, &Bg[(wave * 16 + j * 8) * 64]);
            gl_lds16(bu_src[j] + k0, &Bu[(wave * 16 + j * 8) * 64]);
        }
        __syncthreads();
#pragma unroll
        for (int kk8 = 0; kk8 < 8; kk8 += 4) {
            bf16x8 a[4];
#pragma unroll
            for (int mi = 0; mi < 4; ++mi) {
                const int row = wm + mi * 16 + l16;
                const int pg = (kk8 + quad) ^ (row & 7);
                a[mi] = *(const bf16x8*)&As[row * 64 + pg * 8];
            }
#pragma unroll
            for (int ni = 0; ni < 2; ++ni) {
                const int row = wn + ni * 16 + l16;
                const int pg = (kk8 + quad) ^ (row & 7);
                bf16x8 bg = *(const bf16x8*)&Bg[row * 64 + pg * 8];
                bf16x8 bu = *(const bf16x8*)&Bu[row * 64 + pg * 8];
#pragma unroll
                for (int mi = 0; mi < 4; ++mi) {
                    accG[mi][ni] = __builtin_amdgcn_mfma_f32_16x16x32_bf16(a[mi], bg, accG[mi][ni], 0, 0, 0);
                    accU[mi][ni] = __builtin_amdgcn_mfma_f32_16x16x32_bf16(a[mi], bu, accU[mi][ni], 0, 0, 0);
                }
            }
        }
        __syncthreads();
    }

#pragma unroll
    for (int mi = 0; mi < 4; ++mi) {
#pragma unroll
        for (int r = 0; r < 4; ++r) {
            const int gm = m_base + wm + mi * 16 + quad * 4 + r;
            if (gm < n_e) {
#pragma unroll
                for (int ni = 0; ni < 2; ++ni) {
                    const int f = n_base + wn + ni * 16 + l16;
                    const float gv = accG[mi][ni][r];
                    const float uv = accU[mi][ni][r];
                    hid[(size_t)(off_e + gm) * FD + f] = f2b((gv / (1.f + expf(-gv))) * uv);
                }
            }
        }
    }
}

// ---------------- kernel 6: grouped GEMM2 — Y[pos] = gate*(hid@downT), bf16 ----------------
// BM=128, BN=128. Wave tile 64M x 64N. Grid: 1D, 8 n-panels x MAX_MB = 2112.
__global__ __launch_bounds__(256, 4) void gemm2_kernel(
    const short* __restrict__ hid, const short* __restrict__ down_b,
    const int* __restrict__ counts, const int* __restrict__ offs,
    const float* __restrict__ asg_g, const int* __restrict__ tbl_n,
    const int* __restrict__ blk_e, const int* __restrict__ blk_m,
    short* __restrict__ Y)
{
    __shared__ short As[128 * 64];
    __shared__ short Bs[128 * 64];

    const int wg  = blockIdx.x;
    const int swz = (wg & 7) * (8 * MAX_MB / 8) + (wg >> 3);
    const int m_id = swz >> 3;          // 8 n-panels per m-block
    const int n_base = (swz & 7) * 128;
    if (m_id >= tbl_n[0]) return;
    const int e = blk_e[m_id];
    const int m_base = blk_m[m_id];
    const int n_e = counts[e];
    const int off_e = offs[e];

    const int tid = threadIdx.x;
    const int wave = tid >> 6, lane = tid & 63;
    const int lr = lane >> 3, lg = lane & 7;
    const int sg = lg ^ lr;

    const short* a_src[4]; const short* b_src[4];
    const short* bwp = down_b + (size_t)e * HD * FD;
#pragma unroll
    for (int j = 0; j < 4; ++j) {
        const int r = wave * 32 + j * 8 + lr;
        const int gm = m_base + r;
        const size_t srow = (size_t)(off_e + (gm < n_e ? gm : 0));
        a_src[j] = hid + srow * FD + sg * 8;
        b_src[j] = bwp + (size_t)(n_base + r) * FD + sg * 8;
    }

    const int wm = (wave >> 1) * 64;
    const int wn = (wave & 1) * 64;
    const int quad = lane >> 4, l16 = lane & 15;

    f32x4 acc[4][4];
#pragma unroll
    for (int mi = 0; mi < 4; ++mi)
#pragma unroll
        for (int ni = 0; ni < 4; ++ni) acc[mi][ni] = (f32x4){0,0,0,0};

    for (int t = 0; t < 16; ++t) {
        const int k0 = t * 64;
#pragma unroll
        for (int j = 0; j < 4; ++j) {
            gl_lds16(a_src[j] + k0, &As[(wave * 32 + j * 8) * 64]);
            gl_lds16(b_src[j] + k0, &Bs[(wave * 32 + j * 8) * 64]);
        }
        __syncthreads();
#pragma unroll
        for (int kk8 = 0; kk8 < 8; kk8 += 4) {
            bf16x8 a[4], b[4];
#pragma unroll
            for (int mi = 0; mi < 4; ++mi) {
                const int row = wm + mi * 16 + l16;
                const int pg = (kk8 + quad) ^ (row & 7);
                a[mi] = *(const bf16x8*)&As[row * 64 + pg * 8];
            }
#pragma unroll
            for (int ni = 0; ni < 4; ++ni) {
                const int row = wn + ni * 16 + l16;
                const int pg = (kk8 + quad) ^ (row & 7);
                b[ni] = *(const bf16x8*)&Bs[row * 64 + pg * 8];
            }
#pragma unroll
            for (int mi = 0; mi < 4; ++mi)
#pragma unroll
                for (int ni = 0; ni < 4; ++ni)
                    acc[mi][ni] = __builtin_amdgcn_mfma_f32_16x16x32_bf16(a[mi], b[ni], acc[mi][ni], 0, 0, 0);
        }
        __syncthreads();
    }

#pragma unroll
    for (int mi = 0; mi < 4; ++mi) {
#pragma unroll
        for (int r = 0; r < 4; ++r) {
            const int gm = m_base + wm + mi * 16 + quad * 4 + r;
            if (gm < n_e) {
                const int pos = off_e + gm;
                const float gate = asg_g[pos];
                short* yrow = Y + (size_t)pos * HD;
#pragma unroll
                for (int ni = 0; ni < 4; ++ni) {
                    const int n = n_base + wn + ni * 16 + l16;
                    yrow[n] = f2b(acc[mi][ni][r] * gate);
                }
            }
        }
    }
}

// ---------------- kernel 7: combine — out[t] = Y[p0] + Y[p1] (fp32) ----------------
__global__ __launch_bounds__(256) void combine_kernel(
    const short* __restrict__ Y, const int* __restrict__ tok_pos, float* __restrict__ out)
{
    const int g = blockIdx.x * 256 + threadIdx.x;   // 8 elems/thread
    const int t  = g >> 7;
    const int w8 = (g & 127) * 8;
    const int p0 = tok_pos[2 * t], p1 = tok_pos[2 * t + 1];
    const bf16x8 y0 = *(const bf16x8*)(Y + (size_t)p0 * HD + w8);
    const bf16x8 y1 = *(const bf16x8*)(Y + (size_t)p1 * HD + w8);
    float4 o0, o1;
    o0.x = b2f(y0[0]) + b2f(y1[0]); o0.y = b2f(y0[1]) + b2f(y1[1]);
    o0.z = b2f(y0[2]) + b2f(y1[2]); o0.w = b2f(y0[3]) + b2f(y1[3]);
    o1.x = b2f(y0[4]) + b2f(y1[4]); o1.y = b2f(y0[5]) + b2f(y1[5]);
    o1.z = b2f(y0[6]) + b2f(y1[6]); o1.w = b2f(y0[7]) + b2f(y1[7]);
    float* orow = out + (size_t)t * HD + w8;
    *(float4*)orow = o0;
    *(float4*)(orow + 4) = o1;
}

// ---------------- launch ----------------
extern "C" void kernel_launch(void* const* d_in, const int* in_sizes, int n_in,
                              void* d_out, int out_size, void* d_ws, size_t ws_size,
                              hipStream_t stream)
{
    const float* x  = (const float*)d_in[0];
    const float* rw = (const float*)d_in[1];
    const float* gw = (const float*)d_in[2];
    const float* uw = (const float*)d_in[3];
    const float* dw = (const float*)d_in[4];
    float* out = (float*)d_out;

    char* ws = (char*)d_ws;
    float* usage = (float*)(ws + WS_USAGE);
    int* counts  = (int*)(ws + WS_COUNTS);
    int* offs    = (int*)(ws + WS_OFFS);
    int* cursor  = (int*)(ws + WS_CURSOR);
    int* tbl_n   = (int*)(ws + WS_TBLN);
    int* blk_e   = (int*)(ws + WS_BLKE);
    int* blk_m   = (int*)(ws + WS_BLKM);
    int* tok_e   = (int*)(ws + WS_TOKE);
    float* tok_g = (float*)(ws + WS_TOKG);
    int* tok_pos = (int*)(ws + WS_TOKP);
    int* asg_tok = (int*)(ws + WS_ATOK);
    float* asg_g = (float*)(ws + WS_AGATE);
    short* xb    = (short*)(ws + WS_XB);
    short* gwb   = (short*)(ws + WS_GWB);
    short* uwb   = (short*)(ws + WS_UWB);
    short* dwb   = (short*)(ws + WS_DWB);
    short* hid   = (short*)(ws + WS_HID);
    short* Y     = (short*)(ws + WS_Y);   // aliases xb/gwb/uwb (dead after gemm1)

    cvt3_kernel<<<dim3((NE * FD * HD / 8) / 256, 3), 256, 0, stream>>>(
        gw, uw, dw, gwb, uwb, dwb, (int*)ws);
    router_kernel<<<N_TOK / 8, 512, 0, stream>>>(x, rw, usage, counts, tok_e, tok_g, xb);
    offsets_lb_kernel<<<1, 64, 0, stream>>>(usage, counts, offs, out + 16777216,
                                            tbl_n, blk_e, blk_m);
    scatter_kernel<<<NA / 256, 256, 0, stream>>>(tok_e, tok_g, offs, cursor,
                                                 asg_tok, asg_g, tok_pos);
    gemm1_kernel<<<16 * MAX_MB, 256, 0, stream>>>(
        xb, gwb, uwb, counts, offs, asg_tok, tbl_n, blk_e, blk_m, hid);
    gemm2_kernel<<<8 * MAX_MB, 256, 0, stream>>>(
        hid, dwb, counts, offs, asg_g, tbl_n, blk_e, blk_m, Y);
    combine_kernel<<<(N_TOK * HD / 8) / 256, 256, 0, stream>>>(Y, tok_pos, out);
}

// Round 10
// 451.891 us; speedup vs baseline: 1.1523x; 1.0272x over previous
//
#include <hip/hip_runtime.h>
#include <math.h>

// ---------------- problem constants ----------------
#define N_TOK 16384        // B*T
#define HD    1024         // hidden
#define FD    1024         // expert ffn dim
#define NE    8            // experts
#define NA    (N_TOK * 2)  // assignments (top-2)
#define MBLK  128          // GEMM m-block rows
#define MAX_MB 264         // max m-block-table entries: 32768/128 + 8

typedef __attribute__((ext_vector_type(8))) short bf16x8;
typedef __attribute__((ext_vector_type(4))) short bf16x4;
typedef __attribute__((ext_vector_type(4))) float f32x4;

// ---------------- workspace layout (bytes) ----------------
#define WS_USAGE  0u
#define WS_COUNTS 64u                   // int[8]
#define WS_CURSOR 192u                  // int[8]
#define WS_TOKE   8192u                 // int[NA]
#define WS_TOKG   (WS_TOKE + NA * 4u)   // float[NA]
#define WS_TOKP   (WS_TOKG + NA * 4u)   // int[NA]
#define WS_ATOK   (WS_TOKP + NA * 4u)   // int[NA]
#define WS_AGATE  (WS_ATOK + NA * 4u)   // float[NA]
#define WS_XB     (1u << 20)                      // bf16[N_TOK*HD] 33.5 MB
#define WS_GWB    (WS_XB  + 33554432u)            // bf16[8M]
#define WS_UWB    (WS_GWB + 16777216u)            // bf16[8M]
#define WS_DWB    (WS_UWB + 16777216u)            // bf16[8M]
#define WS_HID    (WS_DWB + 16777216u)            // bf16[NA*FD] 67 MB
#define WS_Y      WS_XB   // alias: Y overlays xb+gwb+uwb (dead after gemm1)

__device__ __forceinline__ short f2b(float f) {  // fp32 -> bf16 RNE
    union { float f; unsigned u; } c;
    c.f = f;
    unsigned u = (c.u + 0x7fffu + ((c.u >> 16) & 1u)) >> 16;
    return (short)u;
}
__device__ __forceinline__ float b2f(short s) {
    union { unsigned u; float f; } c;
    c.u = ((unsigned)(unsigned short)s) << 16;
    return c.f;
}

// async 16B/lane global -> LDS (dest = wave-uniform base + lane*16)
__device__ __forceinline__ void gl_lds16(const short* g, short* l) {
    __builtin_amdgcn_global_load_lds(
        (const __attribute__((address_space(1))) unsigned int*)g,
        (__attribute__((address_space(3))) unsigned int*)l,
        16, 0, 0);
}

// expert partition from counts[8]: map m-block id -> (e, m_base, off_e, n_e).
// Deterministic walk identical to the old offsets_lb table build.
// Returns 0 if m_id beyond last block.
__device__ __forceinline__ int partition_lookup(
    const int* __restrict__ counts, int m_id,
    int* e_out, int* m_base, int* off_e, int* n_e)
{
    int off = 0, rem = m_id, found = 0, e = 0, cnt = 0;
#pragma unroll
    for (int ee = 0; ee < NE; ++ee) {
        const int c = counts[ee];
        const int nb = (c + MBLK - 1) >> 7;   // blocks for this expert
        if (!found) {
            if (rem >= nb) { rem -= nb; off += c; }
            else { e = ee; cnt = c; found = 1; }
        }
    }
    *e_out = e; *m_base = rem * MBLK; *off_e = off; *n_e = cnt;
    return found;
}

// ---------------- kernel 1: FUSED weight-cvt + router ----------------
// 512 thr. Blocks [0,2048): router (8 tokens each, fused x->bf16).
// Blocks [2048,8192): fp32->bf16 weight conversion (3 tensors x 2048 blocks).
// The two parts touch disjoint data; fusing removes one launch serialization
// and overlaps router's LDS/VALU phase with cvt's pure-BW streaming.
#define RTR_BLKS 2048
__global__ __launch_bounds__(512) void cvt_router_kernel(
    const float* __restrict__ x, const float* __restrict__ rw,
    const float* __restrict__ gw, const float* __restrict__ uw, const float* __restrict__ dw,
    short* __restrict__ gwb, short* __restrict__ uwb, short* __restrict__ dwb,
    float* __restrict__ usage, int* __restrict__ counts,
    int* __restrict__ tok_e, float* __restrict__ tok_g, short* __restrict__ xb)
{
    __shared__ float rws[NE * HD];
    __shared__ float usage_s[NE];
    __shared__ int counts_s[NE];
    const int tid = threadIdx.x;
    const int blk = blockIdx.x;

    if (blk >= RTR_BLKS) {
        // ---- weight conversion part ----
        const int cb = blk - RTR_BLKS;
        const int tensor = cb >> 11;           // 2048 blocks per tensor
        const float* in  = (tensor == 0) ? gw  : (tensor == 1) ? uw  : dw;
        short*       out = (tensor == 0) ? gwb : (tensor == 1) ? uwb : dwb;
        const int i = (cb & 2047) * 512 + tid; // 8 elems/thread, 8M elems/tensor
        const float4 a = ((const float4*)in)[2 * i];
        const float4 b = ((const float4*)in)[2 * i + 1];
        bf16x8 o;
        o[0] = f2b(a.x); o[1] = f2b(a.y); o[2] = f2b(a.z); o[3] = f2b(a.w);
        o[4] = f2b(b.x); o[5] = f2b(b.y); o[6] = f2b(b.z); o[7] = f2b(b.w);
        ((bf16x8*)out)[i] = o;
        return;
    }

    // ---- router part ----
    if (tid < NE) { usage_s[tid] = 0.f; counts_s[tid] = 0; }
    for (int c = tid; c < NE * HD / 4; c += 512)
        ((float4*)rws)[c] = ((const float4*)rw)[c];
    __syncthreads();

    const int wave = tid >> 6, lane = tid & 63;
    const int t = blk * 8 + wave;
    float acc[NE];
#pragma unroll
    for (int e = 0; e < NE; ++e) acc[e] = 0.f;
    const float* xrow = x + (size_t)t * HD;
    short* xbrow = xb + (size_t)t * HD;
#pragma unroll
    for (int j = 0; j < 4; ++j) {
        const int h0 = (j * 64 + lane) * 4;
        const float4 xv = *(const float4*)(xrow + h0);
        bf16x4 xc;
        xc[0] = f2b(xv.x); xc[1] = f2b(xv.y); xc[2] = f2b(xv.z); xc[3] = f2b(xv.w);
        *(bf16x4*)(xbrow + h0) = xc;
#pragma unroll
        for (int e = 0; e < NE; ++e) {
            const float4 wv = *(const float4*)&rws[e * HD + h0];
            acc[e] += xv.x * wv.x + xv.y * wv.y + xv.z * wv.z + xv.w * wv.w;
        }
    }
#pragma unroll
    for (int e = 0; e < NE; ++e)
#pragma unroll
        for (int off = 32; off > 0; off >>= 1)
            acc[e] += __shfl_xor(acc[e], off, 64);

    if (lane == 0) {
        float mx = acc[0];
        for (int e = 1; e < NE; ++e) mx = fmaxf(mx, acc[e]);
        float p[NE], Z = 0.f;
        for (int e = 0; e < NE; ++e) { p[e] = expf(acc[e] - mx); Z += p[e]; }
        const float invZ = 1.f / Z;
        for (int e = 0; e < NE; ++e) { p[e] *= invZ; atomicAdd(&usage_s[e], p[e]); }
        int i0 = 0;
        for (int e = 1; e < NE; ++e) if (acc[e] > acc[i0]) i0 = e;
        int i1 = (i0 == 0) ? 1 : 0;
        for (int e = 0; e < NE; ++e) if (e != i0 && acc[e] > acc[i1]) i1 = e;
        const float gs = 1.f / (p[i0] + p[i1]);
        tok_e[2 * t] = i0;  tok_e[2 * t + 1] = i1;
        tok_g[2 * t] = p[i0] * gs;  tok_g[2 * t + 1] = p[i1] * gs;
        atomicAdd(&counts_s[i0], 1); atomicAdd(&counts_s[i1], 1);
    }
    __syncthreads();
    if (tid < NE) {
        atomicAdd(&usage[tid], usage_s[tid]);
        atomicAdd(&counts[tid], counts_s[tid]);
    }
}

// ---------------- kernel 2: scatter (block-aggregated) + lb_loss fold ----------------
// offs computed locally per block from counts (prefix over 8 — removes the
// offsets_lb kernel); block 0 thread 0 also computes lb_loss.
__global__ __launch_bounds__(256) void scatter_kernel(
    const int* __restrict__ tok_e, const float* __restrict__ tok_g,
    const int* __restrict__ counts, const float* __restrict__ usage,
    int* __restrict__ cursor,
    int* __restrict__ asg_tok, float* __restrict__ asg_g,
    int* __restrict__ tok_pos, float* __restrict__ lb_out)
{
    __shared__ int cnt_s[NE];
    __shared__ int base_s[NE];
    const int tid = threadIdx.x;
    if (tid < NE) cnt_s[tid] = 0;
    __syncthreads();

    const int idx = blockIdx.x * 256 + tid;
    const int e = tok_e[idx];
    const int local = atomicAdd(&cnt_s[e], 1);   // LDS atomic: cheap
    __syncthreads();

    if (tid < NE) base_s[tid] = atomicAdd(&cursor[tid], cnt_s[tid]);  // 8 global atomics/block
    __syncthreads();

    // local offs prefix (all threads compute identically; 8 iterations)
    int offs_e = 0;
#pragma unroll
    for (int ee = 0; ee < NE; ++ee) if (ee < e) offs_e += counts[ee];

    const int pos = offs_e + base_s[e] + local;
    asg_tok[pos] = idx >> 1;
    asg_g[pos] = tok_g[idx];
    tok_pos[idx] = pos;

    if (blockIdx.x == 0 && tid == 0) {
        float s = 0.f;
#pragma unroll
        for (int ee = 0; ee < NE; ++ee) {
            const float u = usage[ee] * (1.f / (float)N_TOK);
            s += u * u;
        }
        lb_out[0] = 0.01f * 8.f * s;
    }
}

// ============================================================================
// Grouped GEMMs — round-5 proven geometry (962 TF effective) + two deltas:
// (1) self-partition from counts[8] (no blk tables / offsets kernel);
// (2) HOISTED LDS read offsets: round-9 PMC showed MfmaUtil 46 + VALUBusy 45
//     (= 91% combined issue, m114 co-schedule) at VGPR=64 — the compiler was
//     rematerializing the loop-invariant XOR-swizzle addresses every K-tile.
//     aoff/boff int arrays (compile-time indexed, rule #20 safe) force them
//     live; VGPR ~64->~90 stays under the 128 cap for 4 blocks/CU.
// ============================================================================

// ---------------- kernel 3: grouped GEMM1 — hid = silu(x@gateT)*(x@upT) ----------------
// BM=128, BN=64 dual-B. Wave tile 64M x 32N for both gate and up.
// Grid: 1D, 16 n-panels x MAX_MB m-blocks = 4224 (divisible by 8).
__global__ __launch_bounds__(256, 4) void gemm1_kernel(
    const short* __restrict__ xb, const short* __restrict__ gate_b,
    const short* __restrict__ up_b, const int* __restrict__ counts,
    const int* __restrict__ asg_tok, short* __restrict__ hid)
{
    __shared__ short As[128 * 64];
    __shared__ short Bg[64 * 64];
    __shared__ short Bu[64 * 64];

    // XCD swizzle: same XCD gets consecutive swz -> A-tile L2 reuse.
    const int wg  = blockIdx.x;
    const int swz = (wg & 7) * (16 * MAX_MB / 8) + (wg >> 3);
    const int m_id = swz >> 4;          // 16 n-panels per m-block
    const int n_base = (swz & 15) * 64;

    int e, m_base, off_e, n_e;
    if (!partition_lookup(counts, m_id, &e, &m_base, &off_e, &n_e)) return;

    const int tid = threadIdx.x;
    const int wave = tid >> 6, lane = tid & 63;
    const int lr = lane >> 3, lg = lane & 7;
    const int sg = lg ^ lr;

    const short* a_src[4];
#pragma unroll
    for (int j = 0; j < 4; ++j) {
        const int r = wave * 32 + j * 8 + lr;
        const int gm = m_base + r;
        const int tok = asg_tok[off_e + (gm < n_e ? gm : 0)];
        a_src[j] = xb + (size_t)tok * HD + sg * 8;
    }
    const short* gwp = gate_b + (size_t)e * FD * HD;
    const short* uwp = up_b + (size_t)e * FD * HD;
    const short* bg_src[2]; const short* bu_src[2];
#pragma unroll
    for (int j = 0; j < 2; ++j) {
        const int r = wave * 16 + j * 8 + lr;
        bg_src[j] = gwp + (size_t)(n_base + r) * HD + sg * 8;
        bu_src[j] = uwp + (size_t)(n_base + r) * HD + sg * 8;
    }

    const int wm = (wave >> 1) * 64;
    const int wn = (wave & 1) * 32;
    const int quad = lane >> 4, l16 = lane & 15;

    // hoisted loop-invariant LDS read offsets (short-index units)
    int aoff[2][4], boff[2][2];
#pragma unroll
    for (int s = 0; s < 2; ++s) {
#pragma unroll
        for (int mi = 0; mi < 4; ++mi) {
            const int row = wm + mi * 16 + l16;
            aoff[s][mi] = row * 64 + (((s * 4 + quad) ^ (row & 7)) * 8);
        }
#pragma unroll
        for (int ni = 0; ni < 2; ++ni) {
            const int row = wn + ni * 16 + l16;
            boff[s][ni] = row * 64 + (((s * 4 + quad) ^ (row & 7)) * 8);
        }
    }

    f32x4 accG[4][2], accU[4][2];
#pragma unroll
    for (int mi = 0; mi < 4; ++mi)
#pragma unroll
        for (int ni = 0; ni < 2; ++ni) { accG[mi][ni] = (f32x4){0,0,0,0}; accU[mi][ni] = (f32x4){0,0,0,0}; }

    for (int t = 0; t < 16; ++t) {
        const int k0 = t * 64;
#pragma unroll
        for (int j = 0; j < 4; ++j)
            gl_lds16(a_src[j] + k0, &As[(wave * 32 + j * 8) * 64]);
#pragma unroll
        for (int j = 0; j < 2; ++j) {
            gl_lds16(bg_src[j] + k0, &Bg[(wave * 16 + j * 8) * 64]);
            gl_lds16(bu_src[j] + k0, &Bu[(wave * 16 + j * 8) * 64]);
        }
        __syncthreads();
#pragma unroll
        for (int s = 0; s < 2; ++s) {
            bf16x8 a[4];
#pragma unroll
            for (int mi = 0; mi < 4; ++mi)
                a[mi] = *(const bf16x8*)&As[aoff[s][mi]];
#pragma unroll
            for (int ni = 0; ni < 2; ++ni) {
                const bf16x8 bg = *(const bf16x8*)&Bg[boff[s][ni]];
                const bf16x8 bu = *(const bf16x8*)&Bu[boff[s][ni]];
#pragma unroll
                for (int mi = 0; mi < 4; ++mi) {
                    accG[mi][ni] = __builtin_amdgcn_mfma_f32_16x16x32_bf16(a[mi], bg, accG[mi][ni], 0, 0, 0);
                    accU[mi][ni] = __builtin_amdgcn_mfma_f32_16x16x32_bf16(a[mi], bu, accU[mi][ni], 0, 0, 0);
                }
            }
        }
        __syncthreads();
    }

#pragma unroll
    for (int mi = 0; mi < 4; ++mi) {
#pragma unroll
        for (int r = 0; r < 4; ++r) {
            const int gm = m_base + wm + mi * 16 + quad * 4 + r;
            if (gm < n_e) {
#pragma unroll
                for (int ni = 0; ni < 2; ++ni) {
                    const int f = n_base + wn + ni * 16 + l16;
                    const float gv = accG[mi][ni][r];
                    const float uv = accU[mi][ni][r];
                    hid[(size_t)(off_e + gm) * FD + f] = f2b((gv / (1.f + expf(-gv))) * uv);
                }
            }
        }
    }
}

// ---------------- kernel 4: grouped GEMM2 — Y[pos] = gate*(hid@downT), bf16 ----------------
// BM=128, BN=128. Wave tile 64M x 64N. Grid: 1D, 8 n-panels x MAX_MB = 2112.
__global__ __launch_bounds__(256, 4) void gemm2_kernel(
    const short* __restrict__ hid, const short* __restrict__ down_b,
    const int* __restrict__ counts, const float* __restrict__ asg_g,
    short* __restrict__ Y)
{
    __shared__ short As[128 * 64];
    __shared__ short Bs[128 * 64];

    const int wg  = blockIdx.x;
    const int swz = (wg & 7) * (8 * MAX_MB / 8) + (wg >> 3);
    const int m_id = swz >> 3;          // 8 n-panels per m-block
    const int n_base = (swz & 7) * 128;

    int e, m_base, off_e, n_e;
    if (!partition_lookup(counts, m_id, &e, &m_base, &off_e, &n_e)) return;

    const int tid = threadIdx.x;
    const int wave = tid >> 6, lane = tid & 63;
    const int lr = lane >> 3, lg = lane & 7;
    const int sg = lg ^ lr;

    const short* a_src[4]; const short* b_src[4];
    const short* bwp = down_b + (size_t)e * HD * FD;
#pragma unroll
    for (int j = 0; j < 4; ++j) {
        const int r = wave * 32 + j * 8 + lr;
        const int gm = m_base + r;
        const size_t srow = (size_t)(off_e + (gm < n_e ? gm : 0));
        a_src[j] = hid + srow * FD + sg * 8;
        b_src[j] = bwp + (size_t)(n_base + r) * FD + sg * 8;
    }

    const int wm = (wave >> 1) * 64;
    const int wn = (wave & 1) * 64;
    const int quad = lane >> 4, l16 = lane & 15;

    int aoff[2][4], boff[2][4];
#pragma unroll
    for (int s = 0; s < 2; ++s) {
#pragma unroll
        for (int mi = 0; mi < 4; ++mi) {
            const int row = wm + mi * 16 + l16;
            aoff[s][mi] = row * 64 + (((s * 4 + quad) ^ (row & 7)) * 8);
        }
#pragma unroll
        for (int ni = 0; ni < 4; ++ni) {
            const int row = wn + ni * 16 + l16;
            boff[s][ni] = row * 64 + (((s * 4 + quad) ^ (row & 7)) * 8);
        }
    }

    f32x4 acc[4][4];
#pragma unroll
    for (int mi = 0; mi < 4; ++mi)
#pragma unroll
        for (int ni = 0; ni < 4; ++ni) acc[mi][ni] = (f32x4){0,0,0,0};

    for (int t = 0; t < 16; ++t) {
        const int k0 = t * 64;
#pragma unroll
        for (int j = 0; j < 4; ++j) {
            gl_lds16(a_src[j] + k0, &As[(wave * 32 + j * 8) * 64]);
            gl_lds16(b_src[j] + k0, &Bs[(wave * 32 + j * 8) * 64]);
        }
        __syncthreads();
#pragma unroll
        for (int s = 0; s < 2; ++s) {
            bf16x8 a[4], b[4];
#pragma unroll
            for (int mi = 0; mi < 4; ++mi)
                a[mi] = *(const bf16x8*)&As[aoff[s][mi]];
#pragma unroll
            for (int ni = 0; ni < 4; ++ni)
                b[ni] = *(const bf16x8*)&Bs[boff[s][ni]];
#pragma unroll
            for (int mi = 0; mi < 4; ++mi)
#pragma unroll
                for (int ni = 0; ni < 4; ++ni)
                    acc[mi][ni] = __builtin_amdgcn_mfma_f32_16x16x32_bf16(a[mi], b[ni], acc[mi][ni], 0, 0, 0);
        }
        __syncthreads();
    }

#pragma unroll
    for (int mi = 0; mi < 4; ++mi) {
#pragma unroll
        for (int r = 0; r < 4; ++r) {
            const int gm = m_base + wm + mi * 16 + quad * 4 + r;
            if (gm < n_e) {
                const int pos = off_e + gm;
                const float gate = asg_g[pos];
                short* yrow = Y + (size_t)pos * HD;
#pragma unroll
                for (int ni = 0; ni < 4; ++ni) {
                    const int n = n_base + wn + ni * 16 + l16;
                    yrow[n] = f2b(acc[mi][ni][r] * gate);
                }
            }
        }
    }
}

// ---------------- kernel 5: combine — out[t] = Y[p0] + Y[p1] (fp32) ----------------
__global__ __launch_bounds__(256) void combine_kernel(
    const short* __restrict__ Y, const int* __restrict__ tok_pos, float* __restrict__ out)
{
    const int g = blockIdx.x * 256 + threadIdx.x;   // 8 elems/thread
    const int t  = g >> 7;
    const int w8 = (g & 127) * 8;
    const int p0 = tok_pos[2 * t], p1 = tok_pos[2 * t + 1];
    const bf16x8 y0 = *(const bf16x8*)(Y + (size_t)p0 * HD + w8);
    const bf16x8 y1 = *(const bf16x8*)(Y + (size_t)p1 * HD + w8);
    float4 o0, o1;
    o0.x = b2f(y0[0]) + b2f(y1[0]); o0.y = b2f(y0[1]) + b2f(y1[1]);
    o0.z = b2f(y0[2]) + b2f(y1[2]); o0.w = b2f(y0[3]) + b2f(y1[3]);
    o1.x = b2f(y0[4]) + b2f(y1[4]); o1.y = b2f(y0[5]) + b2f(y1[5]);
    o1.z = b2f(y0[6]) + b2f(y1[6]); o1.w = b2f(y0[7]) + b2f(y1[7]);
    float* orow = out + (size_t)t * HD + w8;
    *(float4*)orow = o0;
    *(float4*)(orow + 4) = o1;
}

// ---------------- launch ----------------
extern "C" void kernel_launch(void* const* d_in, const int* in_sizes, int n_in,
                              void* d_out, int out_size, void* d_ws, size_t ws_size,
                              hipStream_t stream)
{
    const float* x  = (const float*)d_in[0];
    const float* rw = (const float*)d_in[1];
    const float* gw = (const float*)d_in[2];
    const float* uw = (const float*)d_in[3];
    const float* dw = (const float*)d_in[4];
    float* out = (float*)d_out;

    char* ws = (char*)d_ws;
    float* usage = (float*)(ws + WS_USAGE);
    int* counts  = (int*)(ws + WS_COUNTS);
    int* cursor  = (int*)(ws + WS_CURSOR);
    int* tok_e   = (int*)(ws + WS_TOKE);
    float* tok_g = (float*)(ws + WS_TOKG);
    int* tok_pos = (int*)(ws + WS_TOKP);
    int* asg_tok = (int*)(ws + WS_ATOK);
    float* asg_g = (float*)(ws + WS_AGATE);
    short* xb    = (short*)(ws + WS_XB);
    short* gwb   = (short*)(ws + WS_GWB);
    short* uwb   = (short*)(ws + WS_UWB);
    short* dwb   = (short*)(ws + WS_DWB);
    short* hid   = (short*)(ws + WS_HID);
    short* Y     = (short*)(ws + WS_Y);   // aliases xb/gwb/uwb (dead after gemm1)

    hipMemsetAsync(d_ws, 0, 256, stream);   // zero usage/counts/cursor (capture-safe)
    cvt_router_kernel<<<RTR_BLKS + 3 * 2048, 512, 0, stream>>>(
        x, rw, gw, uw, dw, gwb, uwb, dwb, usage, counts, tok_e, tok_g, xb);
    scatter_kernel<<<NA / 256, 256, 0, stream>>>(
        tok_e, tok_g, counts, usage, cursor, asg_tok, asg_g, tok_pos, out + 16777216);
    gemm1_kernel<<<16 * MAX_MB, 256, 0, stream>>>(
        xb, gwb, uwb, counts, asg_tok, hid);
    gemm2_kernel<<<8 * MAX_MB, 256, 0, stream>>>(
        hid, dwb, counts, asg_g, Y);
    combine_kernel<<<(N_TOK * HD / 8) / 256, 256, 0, stream>>>(Y, tok_pos, out);
}